// Round 6
// baseline (258.053 us; speedup 1.0000x reference)
//
#include <hip/hip_runtime.h>
#include <hip/hip_bf16.h>

#define D 128          // D_IN == D_OUT
#define KDIM 256       // concatenated K = 2*D
#define BSHIFT 5       // 32 dst nodes per bucket (= fused block tile)
#define CPAD 16        // ints per bucket cursor (64B line padding)
#define MAX_BE 768     // slots per bucket (Poisson(512) + 11 sigma)
#define ROWS 32
#define LDK 264        // 256 + 8 bf16 pad

#define NSCAT 64       // scatter chunk-blocks (was 250)
#define NBKT_CAP 3136  // LDS bucket-array capacity (>= nb = 3125)

typedef __attribute__((ext_vector_type(8))) short short8;
typedef __attribute__((ext_vector_type(4))) float floatx4;

static __device__ __forceinline__ ushort f2bf(float x) {
    __hip_bfloat16 h = __float2bfloat16(x);
    return __builtin_bit_cast(ushort, h);
}

// ---------------------------------------------------------------------------
// Merged partition + prep, one dispatch, 512-thread blocks.
//   blocks [0, NSCAT):        3-pass LDS-reservation scatter, 25000-edge
//                             chunks. P1: histogram chunk's dst -> lhist.
//                             P2: ONE global atomicAdd per (block,bucket)
//                             reserves a contiguous run (200K atomics total,
//                             was 680K in r5 -> RMW fabric traffic 44->13MB).
//                             P3: re-read src/dst (L2-hot by now) and place
//                             at reserved slots via LDS cursors. Runs avg 8
//                             edges (was 2) -> ep write-amp ~50->~13MB.
//                             No sbuf/bbuf staging -> LDS = 25KB only.
//   blocks [NSCAT, +nbF):     feat fp32 -> bf16 (BW-bound, overlaps scatter)
//   blocks [NSCAT+nbF, +64):  Wc = [W_self | W_neigh] bf16
// ---------------------------------------------------------------------------
__global__ __launch_bounds__(512) void k_part_prep(
        const float* __restrict__ feat,
        const float* __restrict__ Wself,
        const float* __restrict__ Wneigh,
        const int* __restrict__ src,
        const int* __restrict__ dst,
        ushort* __restrict__ feat_b,
        ushort* __restrict__ Wc,
        int* __restrict__ gcur,
        uint* __restrict__ ep,
        int nb, int nbF, int nFeat8, int E, int chunk) {
    __shared__ int lhist[NBKT_CAP];   // histogram, reused as place-cursor
    __shared__ int lbase[NBKT_CAP];   // reserved global base per bucket

    const int blk = blockIdx.x;
    const int tid = threadIdx.x;

    if (blk < NSCAT) {
        for (int i = tid; i < NBKT_CAP; i += 512) lhist[i] = 0;
        __syncthreads();

        const int beg = blk * chunk;            // chunk multiple of 4
        const int end = min(E, beg + chunk);    // E multiple of 4
        const int beg4 = beg >> 2;
        const int end4 = end >> 2;

        // ---- P1: histogram over this chunk's dst ----
        for (int i4 = beg4 + tid; i4 < end4; i4 += 512) {
            int4 d = ((const int4*)dst)[i4];
            atomicAdd(&lhist[d.x >> BSHIFT], 1);
            atomicAdd(&lhist[d.y >> BSHIFT], 1);
            atomicAdd(&lhist[d.z >> BSHIFT], 1);
            atomicAdd(&lhist[d.w >> BSHIFT], 1);
        }
        __syncthreads();

        // ---- P2: one global atomic per non-empty bucket ----
        for (int b2 = tid; b2 < nb; b2 += 512) {
            int c = lhist[b2];
            lbase[b2] = c ? atomicAdd(&gcur[b2 * CPAD], c) : 0;
            lhist[b2] = 0;                 // reuse as placement cursor
        }
        __syncthreads();

        // ---- P3: re-read (L2-hot) and place at reserved slots ----
        for (int i4 = beg4 + tid; i4 < end4; i4 += 512) {
            int4 s = ((const int4*)src)[i4];
            int4 d = ((const int4*)dst)[i4];
            int b0, off, slot;
            b0 = d.x >> BSHIFT;
            off = atomicAdd(&lhist[b0], 1);
            slot = lbase[b0] + off;
            if (slot < MAX_BE)
                ep[(size_t)b0 * MAX_BE + slot] = ((uint)s.x << BSHIFT) | (uint)(d.x & 31);
            b0 = d.y >> BSHIFT;
            off = atomicAdd(&lhist[b0], 1);
            slot = lbase[b0] + off;
            if (slot < MAX_BE)
                ep[(size_t)b0 * MAX_BE + slot] = ((uint)s.y << BSHIFT) | (uint)(d.y & 31);
            b0 = d.z >> BSHIFT;
            off = atomicAdd(&lhist[b0], 1);
            slot = lbase[b0] + off;
            if (slot < MAX_BE)
                ep[(size_t)b0 * MAX_BE + slot] = ((uint)s.z << BSHIFT) | (uint)(d.z & 31);
            b0 = d.w >> BSHIFT;
            off = atomicAdd(&lhist[b0], 1);
            slot = lbase[b0] + off;
            if (slot < MAX_BE)
                ep[(size_t)b0 * MAX_BE + slot] = ((uint)s.w << BSHIFT) | (uint)(d.w & 31);
        }
    } else if (blk < NSCAT + nbF) {
        int i = (blk - NSCAT) * 512 + tid;   // one thread per 8 elems
        if (i < nFeat8) {
            const float4* f4 = (const float4*)feat;
            float4 f0 = f4[(size_t)i * 2];
            float4 f1 = f4[(size_t)i * 2 + 1];
            ushort o[8];
            o[0] = f2bf(f0.x); o[1] = f2bf(f0.y);
            o[2] = f2bf(f0.z); o[3] = f2bf(f0.w);
            o[4] = f2bf(f1.x); o[5] = f2bf(f1.y);
            o[6] = f2bf(f1.z); o[7] = f2bf(f1.w);
            *(short8*)(feat_b + (size_t)i * 8) = *(short8*)o;
        }
    } else {
        int idx = (blk - NSCAT - nbF) * 512 + tid;   // < 128*256 = 32768
        if (idx < D * KDIM) {
            int j = idx >> 8;
            int k = idx & 255;
            float v = (k < D) ? Wself[j * D + k] : Wneigh[j * D + (k - D)];
            Wc[idx] = f2bf(v);
        }
    }
}

// ---------------------------------------------------------------------------
// Fused: LDS count-sort of the block's bucket + aggregate + GEMM.
// (verbatim round-5 kernel; measured 99.1-99.9 us across five rounds,
//  FETCH_SIZE pinned at the 187MB compulsory-miss floor)
// ---------------------------------------------------------------------------
__global__ __launch_bounds__(256, 7) void sage_fused(
        const ushort* __restrict__ feat_b,
        const int* __restrict__ bcount,
        const uint* __restrict__ ep,
        const short* __restrict__ Wc,
        float* __restrict__ out,
        int N) {
    __shared__ ushort X[ROWS * LDK];
    __shared__ uint elist[MAX_BE];
    __shared__ int counts[32], offs[32], cur[32];

    const int tid = threadIdx.x;
    const int b = blockIdx.x;
    const int v0 = b * ROWS;

    const int e0 = b * MAX_BE;
    int cnt = min(bcount[b * CPAD], MAX_BE);

    if (tid < 32) { counts[tid] = 0; cur[tid] = 0; }

    // ---- Phase A: self rows, 16 B per load, 2 loads/thread ----
#pragma unroll
    for (int i = 0; i < 2; i++) {
        int idx = tid + i * 256;       // 0..511
        int r = idx >> 4;              // row 0..31
        int c = idx & 15;              // 16B chunk 0..15
        int v = v0 + r;
        short8 f = {0, 0, 0, 0, 0, 0, 0, 0};
        if (v < N) f = *(const short8*)(feat_b + (size_t)v * D + c * 8);
        *(short8*)&X[r * LDK + c * 8] = f;
    }
    __syncthreads();

    // ---- Phase 0a: count ----
    for (int i = tid; i < cnt; i += 256) {
        uint p = ep[e0 + i];
        atomicAdd(&counts[p & 31], 1);
    }
    __syncthreads();
    // ---- Phase 0b: 32-wide exclusive scan (thread 0, trivial) ----
    if (tid == 0) {
        int run = 0;
#pragma unroll
        for (int i = 0; i < 32; i++) { offs[i] = run; run += counts[i]; }
    }
    __syncthreads();
    // ---- Phase 0c: place src ids node-grouped ----
    for (int i = tid; i < cnt; i += 256) {
        uint p = ep[e0 + i];
        int dl = p & 31;
        int slot = offs[dl] + atomicAdd(&cur[dl], 1);
        elist[slot] = p >> BSHIFT;
    }
    __syncthreads();

    // ---- Phase B: neighbor mean (bf16 gather, fp32 accumulate) ----
    {
        const int ln = tid >> 5;       // node slot 0..7
        const int q = tid & 31;        // 4-elem chunk 0..31
        for (int g = 0; g < 4; g++) {
            int r = g * 8 + ln;
            int v = v0 + r;
            float4 acc = make_float4(0.f, 0.f, 0.f, 0.f);
            float rd = 0.f;
            if (v < N) {
                int dg = counts[r];
                int eb = offs[r];
                rd = (dg > 0) ? 1.0f / (float)dg : 0.f;
                int e = 0;
                for (; e + 7 < dg; e += 8) {
                    uint2 p[8];
#pragma unroll
                    for (int j = 0; j < 8; j++) {
                        uint u = elist[eb + e + j];
                        p[j] = *(const uint2*)(feat_b + (size_t)u * D + q * 4);
                    }
#pragma unroll
                    for (int j = 0; j < 8; j++) {
                        acc.x += __uint_as_float(p[j].x << 16);
                        acc.y += __uint_as_float(p[j].x & 0xffff0000u);
                        acc.z += __uint_as_float(p[j].y << 16);
                        acc.w += __uint_as_float(p[j].y & 0xffff0000u);
                    }
                }
                for (; e + 1 < dg; e += 2) {
                    uint ua = elist[eb + e], ub = elist[eb + e + 1];
                    uint2 pa = *(const uint2*)(feat_b + (size_t)ua * D + q * 4);
                    uint2 pb = *(const uint2*)(feat_b + (size_t)ub * D + q * 4);
                    acc.x += __uint_as_float(pa.x << 16) + __uint_as_float(pb.x << 16);
                    acc.y += __uint_as_float(pa.x & 0xffff0000u) + __uint_as_float(pb.x & 0xffff0000u);
                    acc.z += __uint_as_float(pa.y << 16) + __uint_as_float(pb.y << 16);
                    acc.w += __uint_as_float(pa.y & 0xffff0000u) + __uint_as_float(pb.y & 0xffff0000u);
                }
                if (e < dg) {
                    uint u = elist[eb + e];
                    uint2 pa = *(const uint2*)(feat_b + (size_t)u * D + q * 4);
                    acc.x += __uint_as_float(pa.x << 16);
                    acc.y += __uint_as_float(pa.x & 0xffff0000u);
                    acc.z += __uint_as_float(pa.y << 16);
                    acc.w += __uint_as_float(pa.y & 0xffff0000u);
                }
            }
            ushort o[4];
            o[0] = f2bf(acc.x * rd);
            o[1] = f2bf(acc.y * rd);
            o[2] = f2bf(acc.z * rd);
            o[3] = f2bf(acc.w * rd);
            *(ushort2*)&X[r * LDK + D + q * 4] = *(ushort2*)&o[0];
            *(ushort2*)&X[r * LDK + D + q * 4 + 2] = *(ushort2*)&o[2];
        }
    }
    __syncthreads();

    // ---- Phase C: MFMA ----
    const int lane = tid & 63;
    const int w = tid >> 6;
    const int col = lane & 15;
    const int quad = lane >> 4;
    const int rowBase = (w & 1) * 16;
    const int ctBase = (w >> 1) * 4;

    floatx4 o[4];
#pragma unroll
    for (int ct = 0; ct < 4; ct++) o[ct] = (floatx4){0.f, 0.f, 0.f, 0.f};

#pragma unroll
    for (int kt = 0; kt < 8; kt++) {
        int k0 = kt * 32;
        short8 a = *(const short8*)&X[(rowBase + col) * LDK + k0 + quad * 8];
#pragma unroll
        for (int ct = 0; ct < 4; ct++) {
            short8 bfr = *(const short8*)(Wc + ((ctBase + ct) * 16 + col) * KDIM + k0 + quad * 8);
            o[ct] = __builtin_amdgcn_mfma_f32_16x16x32_bf16(a, bfr, o[ct], 0, 0, 0);
        }
    }

    int vbase = v0 + rowBase + quad * 4;
#pragma unroll
    for (int ct = 0; ct < 4; ct++) {
#pragma unroll
        for (int r = 0; r < 4; r++) {
            int v = vbase + r;
            if (v < N) out[(size_t)v * D + (ctBase + ct) * 16 + col] = o[ct][r];
        }
    }
}

// ---------------------------------------------------------------------------
extern "C" void kernel_launch(void* const* d_in, const int* in_sizes, int n_in,
                              void* d_out, int out_size, void* d_ws, size_t ws_size,
                              hipStream_t stream) {
    const float* feat   = (const float*)d_in[0];
    const int*   src    = (const int*)d_in[1];
    const int*   dst    = (const int*)d_in[2];
    const float* Wself  = (const float*)d_in[3];
    const float* Wneigh = (const float*)d_in[4];
    float* out = (float*)d_out;

    const int N = in_sizes[0] / D;               // 100000
    const int E = in_sizes[1];                   // 1600000
    const int nb = (N + ROWS - 1) / ROWS;        // 3125 buckets == fused blocks

    // ---- workspace carve-up ----
    char* ws = (char*)d_ws;
    size_t off = 0;
    auto carve = [&](size_t bytes) {
        char* p = ws + off;
        off = (off + bytes + 255) & ~(size_t)255;
        return p;
    };
    int*    gcur   = (int*)   carve((size_t)nb * CPAD * sizeof(int));       // 200 KB
    uint*   ep     = (uint*)  carve((size_t)nb * MAX_BE * sizeof(uint));    // 9.6 MB
    ushort* feat_b = (ushort*)carve((size_t)N * D * sizeof(ushort));        // 25.6 MB
    ushort* Wc     = (ushort*)carve((size_t)D * KDIM * sizeof(ushort));     // 64 KB

    const int nFeat8 = N * D / 8;             // 1.6M
    const int nbF = (nFeat8 + 511) / 512;     // 3125
    const int nbW = (D * KDIM + 511) / 512;   // 64
    // chunk: multiple of 4 so int4 passes stay aligned (E is mult of 4)
    const int chunk = (((E + NSCAT - 1) / NSCAT) + 3) & ~3;   // 25000

    (void)hipMemsetAsync(gcur, 0, (size_t)nb * CPAD * sizeof(int), stream);

    k_part_prep<<<NSCAT + nbF + nbW, 512, 0, stream>>>(
        feat, Wself, Wneigh, src, dst, feat_b, Wc, gcur, ep,
        nb, nbF, nFeat8, E, chunk);

    sage_fused<<<nb, 256, 0, stream>>>(feat_b, gcur, ep, (const short*)Wc, out, N);
}

// Round 7
// 242.107 us; speedup vs baseline: 1.0659x; 1.0659x over previous
//
#include <hip/hip_runtime.h>
#include <hip/hip_bf16.h>

#define D 128          // D_IN == D_OUT
#define KDIM 256       // concatenated K = 2*D
#define BSHIFT 5       // 32 dst nodes per bucket (= fused block tile)
#define CPAD 16        // ints per bucket cursor (64B line padding)
#define MAX_BE 768     // slots per bucket (Poisson(512) + 11 sigma)
#define ROWS 32
#define LDK 264        // 256 + 8 bf16 pad
#define PCAP 992       // padded elist capacity: 768 + 32*7

#define NSCAT 250      // scatter chunk-blocks (r5 optimum)
#define CHUNK 6400     // edges per scatter block (250*6400 = 1.6M)
#define NBKT_CAP 3136  // LDS bucket-array capacity (>= nb = 3125)

typedef __attribute__((ext_vector_type(8))) short short8;
typedef __attribute__((ext_vector_type(4))) float floatx4;

static __device__ __forceinline__ ushort f2bf(float x) {
    __hip_bfloat16 h = __float2bfloat16(x);
    return __builtin_bit_cast(ushort, h);
}

// ---------------------------------------------------------------------------
// Merged partition + prep, one dispatch, 512-thread blocks.
// (verbatim round-5 structure — measured partition ~56 us; round-6's
//  NSCAT=64 variant regressed from under-parallelization and is reverted)
//   blocks [0, NSCAT):        LDS-aggregated reservation scatter
//   blocks [NSCAT, +nbF):     feat fp32 -> bf16 (BW-bound, overlaps scatter)
//   blocks [NSCAT+nbF, +65):  Wc pack + zero sentinel row feat_b[N]
// ---------------------------------------------------------------------------
__global__ __launch_bounds__(512) void k_part_prep(
        const float* __restrict__ feat,
        const float* __restrict__ Wself,
        const float* __restrict__ Wneigh,
        const int* __restrict__ src,
        const int* __restrict__ dst,
        ushort* __restrict__ feat_b,
        ushort* __restrict__ Wc,
        int* __restrict__ gcur,
        uint* __restrict__ ep,
        int nb, int nbF, int nFeat8, int E, int N) {
    __shared__ uint   sbuf[CHUNK];      // packed (src<<5 | dstLocal)
    __shared__ ushort bbuf[CHUNK];      // bucket id per edge
    __shared__ int    lhist[NBKT_CAP];  // histogram, reused as place-cursor
    __shared__ int    lbase[NBKT_CAP];  // reserved global base per bucket

    const int blk = blockIdx.x;
    const int tid = threadIdx.x;

    if (blk < NSCAT) {
        for (int i = tid; i < NBKT_CAP; i += 512) lhist[i] = 0;
        __syncthreads();

        const int beg = blk * CHUNK;
        const int end = min(E, beg + CHUNK);
        const int cnt = end - beg;

        // ---- pass 1: load edges -> LDS, histogram ----
        for (int i4 = beg / 4 + tid; i4 < end / 4; i4 += 512) {
            int4 s = ((const int4*)src)[i4];
            int4 d = ((const int4*)dst)[i4];
            int li = i4 * 4 - beg;
            sbuf[li + 0] = ((uint)s.x << BSHIFT) | (uint)(d.x & 31);
            sbuf[li + 1] = ((uint)s.y << BSHIFT) | (uint)(d.y & 31);
            sbuf[li + 2] = ((uint)s.z << BSHIFT) | (uint)(d.z & 31);
            sbuf[li + 3] = ((uint)s.w << BSHIFT) | (uint)(d.w & 31);
            int b0 = d.x >> BSHIFT, b1 = d.y >> BSHIFT;
            int b2 = d.z >> BSHIFT, b3 = d.w >> BSHIFT;
            bbuf[li + 0] = (ushort)b0;
            bbuf[li + 1] = (ushort)b1;
            bbuf[li + 2] = (ushort)b2;
            bbuf[li + 3] = (ushort)b3;
            atomicAdd(&lhist[b0], 1);
            atomicAdd(&lhist[b1], 1);
            atomicAdd(&lhist[b2], 1);
            atomicAdd(&lhist[b3], 1);
        }
        __syncthreads();

        // ---- pass 2: one global atomic per non-empty bucket ----
        for (int b2 = tid; b2 < nb; b2 += 512) {
            int c = lhist[b2];
            if (c) lbase[b2] = atomicAdd(&gcur[b2 * CPAD], c);
            lhist[b2] = 0;                 // reuse as placement cursor
        }
        __syncthreads();

        // ---- pass 3: place at reserved slots (LDS atomics only) ----
        for (int i = tid; i < cnt; i += 512) {
            int b2 = bbuf[i];
            int off = atomicAdd(&lhist[b2], 1);
            int slot = lbase[b2] + off;
            if (slot < MAX_BE) ep[(size_t)b2 * MAX_BE + slot] = sbuf[i];
        }
    } else if (blk < NSCAT + nbF) {
        int i = (blk - NSCAT) * 512 + tid;   // one thread per 8 elems
        if (i < nFeat8) {
            const float4* f4 = (const float4*)feat;
            float4 f0 = f4[(size_t)i * 2];
            float4 f1 = f4[(size_t)i * 2 + 1];
            ushort o[8];
            o[0] = f2bf(f0.x); o[1] = f2bf(f0.y);
            o[2] = f2bf(f0.z); o[3] = f2bf(f0.w);
            o[4] = f2bf(f1.x); o[5] = f2bf(f1.y);
            o[6] = f2bf(f1.z); o[7] = f2bf(f1.w);
            *(short8*)(feat_b + (size_t)i * 8) = *(short8*)o;
        }
    } else {
        int idx = (blk - NSCAT - nbF) * 512 + tid;
        if (idx < D * KDIM) {               // Wc pack
            int j = idx >> 8;
            int k = idx & 255;
            float v = (k < D) ? Wself[j * D + k] : Wneigh[j * D + (k - D)];
            Wc[idx] = f2bf(v);
        } else if (idx < D * KDIM + D) {    // zero sentinel row feat_b[N]
            feat_b[(size_t)N * D + (idx - D * KDIM)] = 0;
        }
    }
}

// ---------------------------------------------------------------------------
// Fused: LDS count-sort + aggregate + GEMM.  ONE change vs r5 (99.5us):
// per-node edge lists PADDED to a multiple of 8 with sentinel src=N
// (zero feature row) -> Phase B is a single uniform 8-deep batch loop.
// Previously ~22% of gathers ran in 2-/1-deep tail loops (Poisson(16)
// remainder), capping outstanding-miss concurrency; fused measured only
// 38% of achievable BW, so depth — not bytes — is the limiter.
// LDS: X 16896 + elist 3968 + 384 = 21248 -> 7 blocks/CU (unchanged).
// ---------------------------------------------------------------------------
__global__ __launch_bounds__(256, 7) void sage_fused(
        const ushort* __restrict__ feat_b,
        const int* __restrict__ bcount,
        const uint* __restrict__ ep,
        const short* __restrict__ Wc,
        float* __restrict__ out,
        int N) {
    __shared__ ushort X[ROWS * LDK];
    __shared__ uint elist[PCAP];
    __shared__ int counts[32], offs[32], cur[32];

    const int tid = threadIdx.x;
    const int b = blockIdx.x;
    const int v0 = b * ROWS;

    const int e0 = b * MAX_BE;
    int cnt = min(bcount[b * CPAD], MAX_BE);

    if (tid < 32) { counts[tid] = 0; cur[tid] = 0; }
    // pre-fill elist with sentinel (zero-row src); real edges overwrite
    for (int i = tid; i < PCAP; i += 256) elist[i] = (uint)N;

    // ---- Phase A: self rows, 16 B per load, 2 loads/thread ----
#pragma unroll
    for (int i = 0; i < 2; i++) {
        int idx = tid + i * 256;       // 0..511
        int r = idx >> 4;              // row 0..31
        int c = idx & 15;              // 16B chunk 0..15
        int v = v0 + r;
        short8 f = {0, 0, 0, 0, 0, 0, 0, 0};
        if (v < N) f = *(const short8*)(feat_b + (size_t)v * D + c * 8);
        *(short8*)&X[r * LDK + c * 8] = f;
    }
    __syncthreads();

    // ---- Phase 0a: count ----
    for (int i = tid; i < cnt; i += 256) {
        uint p = ep[e0 + i];
        atomicAdd(&counts[p & 31], 1);
    }
    __syncthreads();
    // ---- Phase 0b: exclusive scan of PADDED counts (thread 0) ----
    if (tid == 0) {
        int run = 0;
#pragma unroll
        for (int i = 0; i < 32; i++) {
            offs[i] = run;
            run += (counts[i] + 7) & ~7;   // pad each node to mult of 8
        }
    }
    __syncthreads();
    // ---- Phase 0c: place src ids node-grouped (pad slots keep sentinel) ----
    for (int i = tid; i < cnt; i += 256) {
        uint p = ep[e0 + i];
        int dl = p & 31;
        int slot = offs[dl] + atomicAdd(&cur[dl], 1);
        elist[slot] = p >> BSHIFT;
    }
    __syncthreads();

    // ---- Phase B: neighbor mean — uniform 8-deep batches only ----
    {
        const int ln = tid >> 5;       // node slot 0..7
        const int q = tid & 31;        // 4-elem chunk 0..31
        for (int g = 0; g < 4; g++) {
            int r = g * 8 + ln;
            int v = v0 + r;
            float4 acc = make_float4(0.f, 0.f, 0.f, 0.f);
            float rd = 0.f;
            if (v < N) {
                int dg = counts[r];                 // real degree (for mean)
                int dgp = (dg + 7) & ~7;            // padded loop bound
                int eb = offs[r];
                rd = (dg > 0) ? 1.0f / (float)dg : 0.f;
                for (int e = 0; e < dgp; e += 8) {
                    uint2 p[8];
#pragma unroll
                    for (int j = 0; j < 8; j++) {
                        uint u = elist[eb + e + j];
                        p[j] = *(const uint2*)(feat_b + (size_t)u * D + q * 4);
                    }
#pragma unroll
                    for (int j = 0; j < 8; j++) {
                        acc.x += __uint_as_float(p[j].x << 16);
                        acc.y += __uint_as_float(p[j].x & 0xffff0000u);
                        acc.z += __uint_as_float(p[j].y << 16);
                        acc.w += __uint_as_float(p[j].y & 0xffff0000u);
                    }
                }
            }
            ushort o[4];
            o[0] = f2bf(acc.x * rd);
            o[1] = f2bf(acc.y * rd);
            o[2] = f2bf(acc.z * rd);
            o[3] = f2bf(acc.w * rd);
            *(ushort2*)&X[r * LDK + D + q * 4] = *(ushort2*)&o[0];
            *(ushort2*)&X[r * LDK + D + q * 4 + 2] = *(ushort2*)&o[2];
        }
    }
    __syncthreads();

    // ---- Phase C: MFMA ----
    const int lane = tid & 63;
    const int w = tid >> 6;
    const int col = lane & 15;
    const int quad = lane >> 4;
    const int rowBase = (w & 1) * 16;
    const int ctBase = (w >> 1) * 4;

    floatx4 o[4];
#pragma unroll
    for (int ct = 0; ct < 4; ct++) o[ct] = (floatx4){0.f, 0.f, 0.f, 0.f};

#pragma unroll
    for (int kt = 0; kt < 8; kt++) {
        int k0 = kt * 32;
        short8 a = *(const short8*)&X[(rowBase + col) * LDK + k0 + quad * 8];
#pragma unroll
        for (int ct = 0; ct < 4; ct++) {
            short8 bfr = *(const short8*)(Wc + ((ctBase + ct) * 16 + col) * KDIM + k0 + quad * 8);
            o[ct] = __builtin_amdgcn_mfma_f32_16x16x32_bf16(a, bfr, o[ct], 0, 0, 0);
        }
    }

    int vbase = v0 + rowBase + quad * 4;
#pragma unroll
    for (int ct = 0; ct < 4; ct++) {
#pragma unroll
        for (int r = 0; r < 4; r++) {
            int v = vbase + r;
            if (v < N) out[(size_t)v * D + (ctBase + ct) * 16 + col] = o[ct][r];
        }
    }
}

// ---------------------------------------------------------------------------
extern "C" void kernel_launch(void* const* d_in, const int* in_sizes, int n_in,
                              void* d_out, int out_size, void* d_ws, size_t ws_size,
                              hipStream_t stream) {
    const float* feat   = (const float*)d_in[0];
    const int*   src    = (const int*)d_in[1];
    const int*   dst    = (const int*)d_in[2];
    const float* Wself  = (const float*)d_in[3];
    const float* Wneigh = (const float*)d_in[4];
    float* out = (float*)d_out;

    const int N = in_sizes[0] / D;               // 100000
    const int E = in_sizes[1];                   // 1600000
    const int nb = (N + ROWS - 1) / ROWS;        // 3125 buckets == fused blocks

    // ---- workspace carve-up ----
    char* ws = (char*)d_ws;
    size_t off = 0;
    auto carve = [&](size_t bytes) {
        char* p = ws + off;
        off = (off + bytes + 255) & ~(size_t)255;
        return p;
    };
    int*    gcur   = (int*)   carve((size_t)nb * CPAD * sizeof(int));          // 200 KB
    uint*   ep     = (uint*)  carve((size_t)nb * MAX_BE * sizeof(uint));       // 9.6 MB
    ushort* feat_b = (ushort*)carve((size_t)(N + 1) * D * sizeof(ushort));     // 25.6 MB (+ zero row)
    ushort* Wc     = (ushort*)carve((size_t)D * KDIM * sizeof(ushort));        // 64 KB

    const int nFeat8 = N * D / 8;             // 1.6M
    const int nbF = (nFeat8 + 511) / 512;     // 3125
    const int nbW = (D * KDIM + D + 511) / 512;   // 65 (Wc + zero row)

    (void)hipMemsetAsync(gcur, 0, (size_t)nb * CPAD * sizeof(int), stream);

    k_part_prep<<<NSCAT + nbF + nbW, 512, 0, stream>>>(
        feat, Wself, Wneigh, src, dst, feat_b, Wc, gcur, ep,
        nb, nbF, nFeat8, E, N);

    sage_fused<<<nb, 256, 0, stream>>>(feat_b, gcur, ep, (const short*)Wc, out, N);
}